// Round 9
// baseline (2498.738 us; speedup 1.0000x reference)
//
#include <hip/hip_runtime.h>

// ---------------------------------------------------------------------------
// VQVAE forward, fp32, MI355X.
// conv3x3 v3: weights in LDS (broadcast), single-buffer LDS input plane
// (stride 32, LDS=40960B -> 4 wgs/CU), halo columns via __shfl (no b32 LDS
// reads -> no bank conflicts), T14 reg-prefetch of next plane.
// Other kernels: unchanged from measured r7 state.
// ---------------------------------------------------------------------------

// ---------------- conv 3x3, stride 1, pad 1, spatial 32x32, B=64 -----------
// grid: (64 imgs, COUT/8), block 256. Thread: row r=t>>3, cols w0..w0+3.
template<int CIN, int COUT, bool RELU_IN, bool RELU_OUT>
__global__ __launch_bounds__(256, 4) void conv3x3_k(
    const float* __restrict__ in, const float* __restrict__ w,
    const float* __restrict__ bias, float* __restrict__ out) {
  __shared__ float wl[CIN * 72];   // [ci][tap(9)][co(8)]  (broadcast reads)
  __shared__ float lin[32 * 32];   // input plane, single buffer, stride 32
  const int t = threadIdx.x;
  const int co0 = blockIdx.y * 8;
  for (int i = t; i < CIN * 72; i += 256) {
    const int ci = i / 72, rem = i % 72;
    const int tap = rem >> 3, co = rem & 7;
    wl[i] = w[((co0 + co) * CIN + ci) * 9 + tap];
  }
  const int img = blockIdx.x;
  const int r  = t >> 3;           // 0..31
  const int c4 = t & 7;
  const int w0 = c4 << 2;          // 0,4,...,28
  const float* ib = in + (size_t)img * CIN * 1024;
  // stage plane 0: sofs == 4*t (r*32+w0 == 4t), fully coalesced
  {
    float4 pv = *(const float4*)(ib + 4 * t);
    if (RELU_IN) {
      pv.x = fmaxf(pv.x, 0.f); pv.y = fmaxf(pv.y, 0.f);
      pv.z = fmaxf(pv.z, 0.f); pv.w = fmaxf(pv.w, 0.f);
    }
    *(float4*)(&lin[4 * t]) = pv;
  }
  __syncthreads();   // covers weights + plane 0

  float acc[4][8];
#pragma unroll
  for (int c = 0; c < 8; ++c) {
    const float b = bias[co0 + c];
#pragma unroll
    for (int p = 0; p < 4; ++p) acc[p][c] = b;
  }

#pragma unroll 1
  for (int ci = 0; ci < CIN; ++ci) {
    float4 nv;
    if (ci + 1 < CIN)   // prefetch next plane into regs; latency hides under FMAs
      nv = *(const float4*)(ib + (size_t)(ci + 1) * 1024 + 4 * t);
    const float* wp = wl + ci * 72;
    float rin[3][6];   // rows r-1..r+1, cols w0-1..w0+4
#pragma unroll
    for (int dy = 0; dy < 3; ++dy) {
      const int rr = r - 1 + dy;
      float4 v;
      if ((unsigned)rr < 32u) {
        v = *(const float4*)(&lin[(rr << 5) + w0]);
      } else {
        v.x = 0.f; v.y = 0.f; v.z = 0.f; v.w = 0.f;
      }
      // halo via cross-lane: left = prev lane's .w, right = next lane's .x
      const float lft = __shfl_up(v.w, 1);
      const float rgt = __shfl_down(v.x, 1);
      rin[dy][0] = (c4 > 0) ? lft : 0.f;   // w0==0 -> pad zero
      rin[dy][1] = v.x; rin[dy][2] = v.y; rin[dy][3] = v.z; rin[dy][4] = v.w;
      rin[dy][5] = (c4 < 7) ? rgt : 0.f;   // w0+4==32 -> pad zero
    }
#pragma unroll
    for (int dy = 0; dy < 3; ++dy)
#pragma unroll
      for (int dx = 0; dx < 3; ++dx) {
        float wv[8];
        *(float4*)(wv)     = *(const float4*)(wp + (dy * 3 + dx) * 8);
        *(float4*)(wv + 4) = *(const float4*)(wp + (dy * 3 + dx) * 8 + 4);
#pragma unroll
        for (int p = 0; p < 4; ++p) {
          const float xv = rin[dy][dx + p];
#pragma unroll
          for (int c = 0; c < 8; ++c) acc[p][c] = fmaf(xv, wv[c], acc[p][c]);
        }
      }
    __syncthreads();   // all reads of lin done
    if (ci + 1 < CIN) {
      if (RELU_IN) {
        nv.x = fmaxf(nv.x, 0.f); nv.y = fmaxf(nv.y, 0.f);
        nv.z = fmaxf(nv.z, 0.f); nv.w = fmaxf(nv.w, 0.f);
      }
      *(float4*)(&lin[4 * t]) = nv;
      __syncthreads(); // lin ready for next iter
    }
  }
#pragma unroll
  for (int c = 0; c < 8; ++c) {
    float4 o;
    o.x = acc[0][c]; o.y = acc[1][c]; o.z = acc[2][c]; o.w = acc[3][c];
    if (RELU_OUT) {
      o.x = fmaxf(o.x, 0.f); o.y = fmaxf(o.y, 0.f);
      o.z = fmaxf(o.z, 0.f); o.w = fmaxf(o.w, 0.f);
    }
    *(float4*)(out + (((size_t)img * COUT + co0 + c) * 32 + r) * 32 + w0) = o;
  }
}

// ---------------- conv 4x4, stride 2, pad 1 --------------------------------
// pieces of 32x32 output; 2 pieces/block. grid: (pieces/2, COUT/8), block 256.
template<int CIN, int COUT, int HOUT, bool RELU_OUT>
__global__ __launch_bounds__(256) void conv4x4s2_k(
    const float* __restrict__ in, const float* __restrict__ w,
    const float* __restrict__ bias, float* __restrict__ out) {
  constexpr int HIN = HOUT * 2;
  constexpr int PW = HOUT / 32;     // pieces per row dim
  constexpr int PPI = PW * PW;
  __shared__ float wl[CIN * 128];   // [ci][tap(16)][co(8)]
  const int t = threadIdx.x;
  const int co0 = blockIdx.y * 8;
  for (int i = t; i < CIN * 128; i += 256) {
    const int ci = i >> 7, rem = i & 127;
    const int tap = rem >> 3, co = rem & 7;
    wl[i] = w[((co0 + co) * CIN + ci) * 16 + tap];
  }
  __syncthreads();
  const int piece = blockIdx.x * 2 + (t >> 7);
  const int img = piece / PPI;
  const int prc = piece % PPI;
  const int pr = prc / PW, pc = prc % PW;
  const int tid = t & 127;
  const int r  = (tid >> 2) + pr * 32;
  const int w0 = ((tid & 3) << 3) + pc * 32;
  float acc[8][8];
#pragma unroll
  for (int c = 0; c < 8; ++c) {
    const float b = bias[co0 + c];
#pragma unroll
    for (int p = 0; p < 8; ++p) acc[p][c] = b;
  }
  const float* ib = in + (size_t)img * CIN * HIN * HIN;
#pragma unroll 1
  for (int ci = 0; ci < CIN; ++ci) {
    const float* ip = ib + (size_t)ci * HIN * HIN;
    const float* wp = wl + ci * 128;
#pragma unroll
    for (int ky = 0; ky < 4; ++ky) {
      const int rr = 2 * r - 1 + ky;
      const bool rok = (unsigned)rr < (unsigned)HIN;
      const float* rp = ip + rr * HIN;
      float rowv[18];                       // cols 2*w0-1 .. 2*w0+16
      if (rok) {
        rowv[0] = (2 * w0 - 1 >= 0) ? rp[2 * w0 - 1] : 0.f;
#pragma unroll
        for (int q = 0; q < 4; ++q)
          *(float4*)(&rowv[1 + 4 * q]) = *(const float4*)(rp + 2 * w0 + 4 * q);
        rowv[17] = (2 * w0 + 16 < HIN) ? rp[2 * w0 + 16] : 0.f;
      } else {
#pragma unroll
        for (int cc = 0; cc < 18; ++cc) rowv[cc] = 0.f;
      }
#pragma unroll
      for (int kx = 0; kx < 4; ++kx) {
        float wv[8];
        *(float4*)(wv)     = *(const float4*)(wp + (ky * 4 + kx) * 8);
        *(float4*)(wv + 4) = *(const float4*)(wp + (ky * 4 + kx) * 8 + 4);
#pragma unroll
        for (int p = 0; p < 8; ++p) {
          const float xv = rowv[2 * p + kx];
#pragma unroll
          for (int c = 0; c < 8; ++c) acc[p][c] = fmaf(xv, wv[c], acc[p][c]);
        }
      }
    }
  }
#pragma unroll
  for (int c = 0; c < 8; ++c) {
    float* op = out + (((size_t)img * COUT + co0 + c) * HOUT + r) * HOUT + w0;
#pragma unroll
    for (int p = 0; p < 8; ++p) {
      float v = acc[p][c];
      if (RELU_OUT) v = fmaxf(v, 0.f);
      op[p] = v;
    }
  }
}

// ---------------- conv transpose 4x4, stride 2, pad 1 ----------------------
// y[ho,wo] = b + sum_ci sum_{ky≡(ho+1)%2, kx≡(wo+1)%2} x[(ho+1-ky)/2,(wo+1-kx)/2]*w[ci,co,ky,kx]
template<int CIN, int COUT, int COCH, int HOUT, bool RELU_OUT>
__global__ __launch_bounds__(256) void convT4x4s2_k(
    const float* __restrict__ in, const float* __restrict__ w,
    const float* __restrict__ bias, float* __restrict__ out) {
  constexpr int HIN = HOUT / 2;
  constexpr int GPR = HOUT / 16;    // 16-wide col groups per row
  constexpr int TPP = 32 * GPR;     // threads per piece (32 rows)
  constexpr int PPB = 256 / TPP;
  constexpr int PPI = HOUT / 32;
  __shared__ float wl[CIN * 16 * COCH];  // [ci][tap(16)][co]
  const int t = threadIdx.x;
  const int co0 = blockIdx.y * COCH;
  for (int i = t; i < CIN * 16 * COCH; i += 256) {
    const int ci = i / (16 * COCH);
    const int rem = i % (16 * COCH);
    const int tap = rem / COCH, co = rem % COCH;
    float v = 0.f;
    if (co0 + co < COUT) v = w[((size_t)ci * COUT + co0 + co) * 16 + tap];
    wl[i] = v;
  }
  __syncthreads();
  const int piece = blockIdx.x * PPB + t / TPP;
  const int img = piece / PPI;
  const int pr = piece % PPI;
  const int tid = t % TPP;
  const int r  = tid / GPR + pr * 32;
  const int w0 = (tid % GPR) * 16;
  float acc[16][COCH];
#pragma unroll
  for (int c = 0; c < COCH; ++c) {
    const float b = (co0 + c < COUT) ? bias[co0 + c] : 0.f;
#pragma unroll
    for (int m = 0; m < 16; ++m) acc[m][c] = b;
  }
  const float* ib = in + (size_t)img * CIN * HIN * HIN;
  const int kyb = (r + 1) & 1;
  const int hi0 = (r + 1 - kyb) >> 1;
#pragma unroll 1
  for (int ci = 0; ci < CIN; ++ci) {
    const float* ip = ib + (size_t)ci * HIN * HIN;
    float rin[2][10];                       // rows hi0, hi0-1; cols w0/2-1 .. w0/2+8
#pragma unroll
    for (int jy = 0; jy < 2; ++jy) {
      const int hh = hi0 - jy;
      const bool rok = (unsigned)hh < (unsigned)HIN;
      const float* rp = ip + hh * HIN;
      const int c0 = (w0 >> 1);
      if (rok) {
        rin[jy][0] = (c0 > 0) ? rp[c0 - 1] : 0.f;
        *(float4*)(&rin[jy][1]) = *(const float4*)(rp + c0);
        *(float4*)(&rin[jy][5]) = *(const float4*)(rp + c0 + 4);
        rin[jy][9] = (c0 + 8 < HIN) ? rp[c0 + 8] : 0.f;
      } else {
#pragma unroll
        for (int cc = 0; cc < 10; ++cc) rin[jy][cc] = 0.f;
      }
    }
    const float* wp = wl + ci * 16 * COCH;
#pragma unroll
    for (int jy = 0; jy < 2; ++jy) {
      const int ky = kyb + 2 * jy;          // uses row hi0-jy
#pragma unroll
      for (int kx = 0; kx < 4; ++kx) {
        const int p = (kx + 1) & 1;         // output col parity served by kx
        const int idx0 = ((p + 1 - kx) >> 1) + 1;
        float wv[COCH];
#pragma unroll
        for (int c = 0; c < COCH; c += 4)
          *(float4*)(wv + c) = *(const float4*)(wp + (ky * 4 + kx) * COCH + c);
#pragma unroll
        for (int m = 0; m < 8; ++m) {
          const float xv = rin[jy][idx0 + m];
#pragma unroll
          for (int c = 0; c < COCH; ++c)
            acc[2 * m + p][c] = fmaf(xv, wv[c], acc[2 * m + p][c]);
        }
      }
    }
  }
#pragma unroll
  for (int c = 0; c < COCH; ++c) {
    if (co0 + c < COUT) {
      float* op = out + (((size_t)img * COUT + co0 + c) * HOUT + r) * HOUT + w0;
#pragma unroll
      for (int m = 0; m < 16; ++m) {
        float v = acc[m][c];
        if (RELU_OUT) v = fmaxf(v, 0.f);
        op[m] = v;
      }
    }
  }
}

// ---------------- conv 1x1 + residual (in-place), 128->128, 32x32 ----------
// grid: (64 imgs, 8 co-chunks of 16), block 256; thread: 4 consecutive pos.
__global__ __launch_bounds__(256) void conv1x1res_k(
    const float* __restrict__ in, const float* __restrict__ w,
    const float* __restrict__ bias, float* __restrict__ io) {
  __shared__ float wl[128 * 16];  // [ci][co(16)]
  const int t = threadIdx.x;
  const int co0 = blockIdx.y * 16;
  for (int i = t; i < 2048; i += 256) {
    const int ci = i >> 4, co = i & 15;
    wl[i] = w[(co0 + co) * 128 + ci];
  }
  __syncthreads();
  const int img = blockIdx.x;
  float acc[4][16];
#pragma unroll
  for (int c = 0; c < 16; ++c) {
    const float b = bias[co0 + c];
#pragma unroll
    for (int p = 0; p < 4; ++p) acc[p][c] = b;
  }
  const float4* ip = (const float4*)(in + (size_t)img * 131072);
#pragma unroll 4
  for (int ci = 0; ci < 128; ++ci) {
    float xv[4];
    *(float4*)xv = ip[ci * 256 + t];
    float wv[16];
#pragma unroll
    for (int c = 0; c < 16; c += 4)
      *(float4*)(wv + c) = *(const float4*)(wl + ci * 16 + c);
#pragma unroll
    for (int p = 0; p < 4; ++p)
#pragma unroll
      for (int c = 0; c < 16; ++c) acc[p][c] = fmaf(xv[p], wv[c], acc[p][c]);
  }
  float4* iop = (float4*)(io + (size_t)img * 131072);
#pragma unroll
  for (int c = 0; c < 16; ++c) {
    float4 v = iop[(co0 + c) * 256 + t];
    v.x += acc[0][c]; v.y += acc[1][c]; v.z += acc[2][c]; v.w += acc[3][c];
    iop[(co0 + c) * 256 + t] = v;
  }
}

// ---------------- VQ -------------------------------------------------------
__global__ __launch_bounds__(256) void vq_prep_k(const float* __restrict__ emb,
    float* __restrict__ e2, float* __restrict__ lossAcc) {
  const int k = blockIdx.x * 256 + threadIdx.x;
  if (k < 512) {
    float s = 0.f;
#pragma unroll
    for (int d = 0; d < 32; ++d) { const float v = emb[k * 32 + d]; s = fmaf(v, v, s); }
    e2[k] = s;
  }
  if (k == 0) lossAcc[0] = 0.f;
}

// one spatial vector per thread; codebook via wave-uniform loads (L1 broadcast).
__global__ __launch_bounds__(256) void vq_k(
    const float* __restrict__ z, const float* __restrict__ emb,
    const float* __restrict__ e2, float* __restrict__ q,
    float* __restrict__ lossAcc) {
  const int n = blockIdx.x * 256 + threadIdx.x;
  const int img = n >> 10, pos = n & 1023;
  const float* zp = z + (size_t)img * 32768 + pos;
  float zv[32];
#pragma unroll
  for (int d = 0; d < 32; ++d) zv[d] = zp[d * 1024];
  float best = 3.4e38f;
  int bk = 0;
  const float4* ev = (const float4*)emb;
#pragma unroll 2
  for (int k = 0; k < 512; ++k) {
    float d0 = 0.f, d1 = 0.f, d2 = 0.f, d3 = 0.f;
#pragma unroll
    for (int j = 0; j < 8; ++j) {
      const float4 e = ev[k * 8 + j];
      d0 = fmaf(zv[4 * j + 0], e.x, d0);
      d1 = fmaf(zv[4 * j + 1], e.y, d1);
      d2 = fmaf(zv[4 * j + 2], e.z, d2);
      d3 = fmaf(zv[4 * j + 3], e.w, d3);
    }
    const float dist = fmaf(-2.f, (d0 + d1) + (d2 + d3), e2[k]);
    if (dist < best) { best = dist; bk = k; }   // strict <  => first argmin
  }
  float ls = 0.f;
  float* qp = q + (size_t)img * 32768 + pos;
#pragma unroll
  for (int d = 0; d < 32; ++d) {
    const float qd = emb[bk * 32 + d];
    qp[d * 1024] = qd;
    const float df = qd - zv[d];
    ls = fmaf(df, df, ls);
  }
#pragma unroll
  for (int off = 32; off > 0; off >>= 1) ls += __shfl_down(ls, off);
  __shared__ float wred[4];
  const int lane = threadIdx.x & 63, wid = threadIdx.x >> 6;
  if (lane == 0) wred[wid] = ls;
  __syncthreads();
  if (threadIdx.x == 0) atomicAdd(lossAcc, (wred[0] + wred[1]) + (wred[2] + wred[3]));
}

__global__ void loss_fin_k(const float* __restrict__ lossAcc, float* __restrict__ o) {
  o[0] = 1.25f * lossAcc[0] * (1.0f / 2097152.0f);
}

// ---------------------------------------------------------------------------
extern "C" void kernel_launch(void* const* d_in, const int* in_sizes, int n_in,
                              void* d_out, int out_size, void* d_ws, size_t ws_size,
                              hipStream_t stream) {
  (void)in_sizes; (void)n_in; (void)out_size; (void)ws_size;
  const float* x      = (const float*)d_in[0];
  const float* ec0_w  = (const float*)d_in[1];  const float* ec0_b = (const float*)d_in[2];
  const float* ec1_w  = (const float*)d_in[3];  const float* ec1_b = (const float*)d_in[4];
  const float* er1a_w = (const float*)d_in[5];  const float* er1a_b = (const float*)d_in[6];
  const float* er1b_w = (const float*)d_in[7];  const float* er1b_b = (const float*)d_in[8];
  const float* er2a_w = (const float*)d_in[9];  const float* er2a_b = (const float*)d_in[10];
  const float* er2b_w = (const float*)d_in[11]; const float* er2b_b = (const float*)d_in[12];
  const float* ec2_w  = (const float*)d_in[13]; const float* ec2_b = (const float*)d_in[14];
  const float* emb    = (const float*)d_in[15];
  const float* dc0_w  = (const float*)d_in[16]; const float* dc0_b = (const float*)d_in[17];
  const float* dr1a_w = (const float*)d_in[18]; const float* dr1a_b = (const float*)d_in[19];
  const float* dr1b_w = (const float*)d_in[20]; const float* dr1b_b = (const float*)d_in[21];
  const float* dr2a_w = (const float*)d_in[22]; const float* dr2a_b = (const float*)d_in[23];
  const float* dr2b_w = (const float*)d_in[24]; const float* dr2b_b = (const float*)d_in[25];
  const float* dt1_w  = (const float*)d_in[26]; const float* dt1_b = (const float*)d_in[27];
  const float* dt2_w  = (const float*)d_in[28]; const float* dt2_b = (const float*)d_in[29];
  float* out = (float*)d_out;
  float* ws  = (float*)d_ws;

  // workspace layout (floats); C/Z/Q overlap the dead ec0 buffer A.
  float* A    = ws;                    // 16777216 (ec0 out; later dt1 out)
  float* B    = ws + 16777216;         //  8388608 (main 128ch stream)
  float* C    = A;                     //  8388608 (res 3x3 tmp)
  float* Z    = A + 8388608;           //  2097152 (encoder z)
  float* Q    = A + 10485760;          //  2097152 (quantized)
  float* E2   = ws + 25165824;         //      512
  float* LACC = ws + 25166336;         //        1

  // encoder
  conv4x4s2_k<3, 64, 64, true><<<dim3(128, 8), 256, 0, stream>>>(x, ec0_w, ec0_b, A);
  conv4x4s2_k<64, 128, 32, true><<<dim3(32, 16), 256, 0, stream>>>(A, ec1_w, ec1_b, B);
  conv3x3_k<128, 128, true, true><<<dim3(64, 16), 256, 0, stream>>>(B, er1a_w, er1a_b, C);
  conv1x1res_k<<<dim3(64, 8), 256, 0, stream>>>(C, er1b_w, er1b_b, B);
  conv3x3_k<128, 128, true, true><<<dim3(64, 16), 256, 0, stream>>>(B, er2a_w, er2a_b, C);
  conv1x1res_k<<<dim3(64, 8), 256, 0, stream>>>(C, er2b_w, er2b_b, B);
  conv3x3_k<128, 32, false, false><<<dim3(64, 4), 256, 0, stream>>>(B, ec2_w, ec2_b, Z);
  // vector quantizer
  vq_prep_k<<<2, 256, 0, stream>>>(emb, E2, LACC);
  vq_k<<<256, 256, 0, stream>>>(Z, emb, E2, Q, LACC);
  // decoder
  conv3x3_k<32, 128, false, false><<<dim3(64, 16), 256, 0, stream>>>(Q, dc0_w, dc0_b, B);
  conv3x3_k<128, 128, true, true><<<dim3(64, 16), 256, 0, stream>>>(B, dr1a_w, dr1a_b, C);
  conv1x1res_k<<<dim3(64, 8), 256, 0, stream>>>(C, dr1b_w, dr1b_b, B);
  conv3x3_k<128, 128, true, true><<<dim3(64, 16), 256, 0, stream>>>(B, dr2a_w, dr2a_b, C);
  conv1x1res_k<<<dim3(64, 8), 256, 0, stream>>>(C, dr2b_w, dr2b_b, B);
  convT4x4s2_k<128, 64, 8, 64, true><<<dim3(64, 8), 256, 0, stream>>>(B, dt1_w, dt1_b, A);
  convT4x4s2_k<64, 3, 4, 128, false><<<dim3(256, 1), 256, 0, stream>>>(A, dt2_w, dt2_b, out);
  // loss
  loss_fin_k<<<1, 1, 0, stream>>>(LACC, out + 3145728);
}

// Round 10
// 2199.593 us; speedup vs baseline: 1.1360x; 1.1360x over previous
//
#include <hip/hip_runtime.h>

// ---------------------------------------------------------------------------
// VQVAE forward, fp32, MI355X.
// conv3x3 v4: weights in LDS (broadcast only), input rows read DIRECT from
// global (L1-resident 4KB plane, 3 coalesced 1KB wave-loads/ci), halo via
// __shfl, ZERO barriers in the ci loop. 36864B LDS -> 4 wgs/CU, 64 VGPR.
// Other kernels: unchanged from measured r7/r9 state.
// ---------------------------------------------------------------------------

// ---------------- conv 3x3, stride 1, pad 1, spatial 32x32, B=64 -----------
// grid: (64 imgs, COUT/8), block 256. Thread: row r=t>>3, cols w0..w0+3.
template<int CIN, int COUT, bool RELU_IN, bool RELU_OUT>
__global__ __launch_bounds__(256, 4) void conv3x3_k(
    const float* __restrict__ in, const float* __restrict__ w,
    const float* __restrict__ bias, float* __restrict__ out) {
  __shared__ float wl[CIN * 72];   // [ci][tap(9)][co(8)]  (broadcast reads)
  const int t = threadIdx.x;
  const int co0 = blockIdx.y * 8;
  for (int i = t; i < CIN * 72; i += 256) {
    const int ci = i / 72, rem = i % 72;
    const int tap = rem >> 3, co = rem & 7;
    wl[i] = w[((co0 + co) * CIN + ci) * 9 + tap];
  }
  __syncthreads();   // weights ready; NO barriers after this point

  const int img = blockIdx.x;
  const int r  = t >> 3;           // 0..31
  const int c4 = t & 7;
  const int w0 = c4 << 2;          // 0,4,...,28
  const float* ib = in + (size_t)img * CIN * 1024;

  float acc[4][8];
#pragma unroll
  for (int c = 0; c < 8; ++c) {
    const float b = bias[co0 + c];
#pragma unroll
    for (int p = 0; p < 4; ++p) acc[p][c] = b;
  }

#pragma unroll 1
  for (int ci = 0; ci < CIN; ++ci) {
    const float* ip = ib + (size_t)ci * 1024;
    const float* wp = wl + ci * 72;
    float rin[3][6];   // rows r-1..r+1, cols w0-1..w0+4
#pragma unroll
    for (int dy = 0; dy < 3; ++dy) {
      const int rr = r - 1 + dy;
      float4 v;
      if ((unsigned)rr < 32u) {
        v = *(const float4*)(ip + (rr << 5) + w0);   // coalesced: wave covers 1KB
        if (RELU_IN) {
          v.x = fmaxf(v.x, 0.f); v.y = fmaxf(v.y, 0.f);
          v.z = fmaxf(v.z, 0.f); v.w = fmaxf(v.w, 0.f);
        }
      } else {
        v.x = 0.f; v.y = 0.f; v.z = 0.f; v.w = 0.f;
      }
      // halo via cross-lane: left = prev lane's .w, right = next lane's .x
      const float lft = __shfl_up(v.w, 1);
      const float rgt = __shfl_down(v.x, 1);
      rin[dy][0] = (c4 > 0) ? lft : 0.f;   // w0==0 -> pad zero
      rin[dy][1] = v.x; rin[dy][2] = v.y; rin[dy][3] = v.z; rin[dy][4] = v.w;
      rin[dy][5] = (c4 < 7) ? rgt : 0.f;   // w0+4==32 -> pad zero
    }
#pragma unroll
    for (int dy = 0; dy < 3; ++dy)
#pragma unroll
      for (int dx = 0; dx < 3; ++dx) {
        float wv[8];
        *(float4*)(wv)     = *(const float4*)(wp + (dy * 3 + dx) * 8);
        *(float4*)(wv + 4) = *(const float4*)(wp + (dy * 3 + dx) * 8 + 4);
#pragma unroll
        for (int p = 0; p < 4; ++p) {
          const float xv = rin[dy][dx + p];
#pragma unroll
          for (int c = 0; c < 8; ++c) acc[p][c] = fmaf(xv, wv[c], acc[p][c]);
        }
      }
  }
#pragma unroll
  for (int c = 0; c < 8; ++c) {
    float4 o;
    o.x = acc[0][c]; o.y = acc[1][c]; o.z = acc[2][c]; o.w = acc[3][c];
    if (RELU_OUT) {
      o.x = fmaxf(o.x, 0.f); o.y = fmaxf(o.y, 0.f);
      o.z = fmaxf(o.z, 0.f); o.w = fmaxf(o.w, 0.f);
    }
    *(float4*)(out + (((size_t)img * COUT + co0 + c) * 32 + r) * 32 + w0) = o;
  }
}

// ---------------- conv 4x4, stride 2, pad 1 --------------------------------
// pieces of 32x32 output; 2 pieces/block. grid: (pieces/2, COUT/8), block 256.
template<int CIN, int COUT, int HOUT, bool RELU_OUT>
__global__ __launch_bounds__(256) void conv4x4s2_k(
    const float* __restrict__ in, const float* __restrict__ w,
    const float* __restrict__ bias, float* __restrict__ out) {
  constexpr int HIN = HOUT * 2;
  constexpr int PW = HOUT / 32;     // pieces per row dim
  constexpr int PPI = PW * PW;
  __shared__ float wl[CIN * 128];   // [ci][tap(16)][co(8)]
  const int t = threadIdx.x;
  const int co0 = blockIdx.y * 8;
  for (int i = t; i < CIN * 128; i += 256) {
    const int ci = i >> 7, rem = i & 127;
    const int tap = rem >> 3, co = rem & 7;
    wl[i] = w[((co0 + co) * CIN + ci) * 16 + tap];
  }
  __syncthreads();
  const int piece = blockIdx.x * 2 + (t >> 7);
  const int img = piece / PPI;
  const int prc = piece % PPI;
  const int pr = prc / PW, pc = prc % PW;
  const int tid = t & 127;
  const int r  = (tid >> 2) + pr * 32;
  const int w0 = ((tid & 3) << 3) + pc * 32;
  float acc[8][8];
#pragma unroll
  for (int c = 0; c < 8; ++c) {
    const float b = bias[co0 + c];
#pragma unroll
    for (int p = 0; p < 8; ++p) acc[p][c] = b;
  }
  const float* ib = in + (size_t)img * CIN * HIN * HIN;
#pragma unroll 1
  for (int ci = 0; ci < CIN; ++ci) {
    const float* ip = ib + (size_t)ci * HIN * HIN;
    const float* wp = wl + ci * 128;
#pragma unroll
    for (int ky = 0; ky < 4; ++ky) {
      const int rr = 2 * r - 1 + ky;
      const bool rok = (unsigned)rr < (unsigned)HIN;
      const float* rp = ip + rr * HIN;
      float rowv[18];                       // cols 2*w0-1 .. 2*w0+16
      if (rok) {
        rowv[0] = (2 * w0 - 1 >= 0) ? rp[2 * w0 - 1] : 0.f;
#pragma unroll
        for (int q = 0; q < 4; ++q)
          *(float4*)(&rowv[1 + 4 * q]) = *(const float4*)(rp + 2 * w0 + 4 * q);
        rowv[17] = (2 * w0 + 16 < HIN) ? rp[2 * w0 + 16] : 0.f;
      } else {
#pragma unroll
        for (int cc = 0; cc < 18; ++cc) rowv[cc] = 0.f;
      }
#pragma unroll
      for (int kx = 0; kx < 4; ++kx) {
        float wv[8];
        *(float4*)(wv)     = *(const float4*)(wp + (ky * 4 + kx) * 8);
        *(float4*)(wv + 4) = *(const float4*)(wp + (ky * 4 + kx) * 8 + 4);
#pragma unroll
        for (int p = 0; p < 8; ++p) {
          const float xv = rowv[2 * p + kx];
#pragma unroll
          for (int c = 0; c < 8; ++c) acc[p][c] = fmaf(xv, wv[c], acc[p][c]);
        }
      }
    }
  }
#pragma unroll
  for (int c = 0; c < 8; ++c) {
    float* op = out + (((size_t)img * COUT + co0 + c) * HOUT + r) * HOUT + w0;
#pragma unroll
    for (int p = 0; p < 8; ++p) {
      float v = acc[p][c];
      if (RELU_OUT) v = fmaxf(v, 0.f);
      op[p] = v;
    }
  }
}

// ---------------- conv transpose 4x4, stride 2, pad 1 ----------------------
// y[ho,wo] = b + sum_ci sum_{ky≡(ho+1)%2, kx≡(wo+1)%2} x[(ho+1-ky)/2,(wo+1-kx)/2]*w[ci,co,ky,kx]
template<int CIN, int COUT, int COCH, int HOUT, bool RELU_OUT>
__global__ __launch_bounds__(256) void convT4x4s2_k(
    const float* __restrict__ in, const float* __restrict__ w,
    const float* __restrict__ bias, float* __restrict__ out) {
  constexpr int HIN = HOUT / 2;
  constexpr int GPR = HOUT / 16;    // 16-wide col groups per row
  constexpr int TPP = 32 * GPR;     // threads per piece (32 rows)
  constexpr int PPB = 256 / TPP;
  constexpr int PPI = HOUT / 32;
  __shared__ float wl[CIN * 16 * COCH];  // [ci][tap(16)][co]
  const int t = threadIdx.x;
  const int co0 = blockIdx.y * COCH;
  for (int i = t; i < CIN * 16 * COCH; i += 256) {
    const int ci = i / (16 * COCH);
    const int rem = i % (16 * COCH);
    const int tap = rem / COCH, co = rem % COCH;
    float v = 0.f;
    if (co0 + co < COUT) v = w[((size_t)ci * COUT + co0 + co) * 16 + tap];
    wl[i] = v;
  }
  __syncthreads();
  const int piece = blockIdx.x * PPB + t / TPP;
  const int img = piece / PPI;
  const int pr = piece % PPI;
  const int tid = t % TPP;
  const int r  = tid / GPR + pr * 32;
  const int w0 = (tid % GPR) * 16;
  float acc[16][COCH];
#pragma unroll
  for (int c = 0; c < COCH; ++c) {
    const float b = (co0 + c < COUT) ? bias[co0 + c] : 0.f;
#pragma unroll
    for (int m = 0; m < 16; ++m) acc[m][c] = b;
  }
  const float* ib = in + (size_t)img * CIN * HIN * HIN;
  const int kyb = (r + 1) & 1;
  const int hi0 = (r + 1 - kyb) >> 1;
#pragma unroll 1
  for (int ci = 0; ci < CIN; ++ci) {
    const float* ip = ib + (size_t)ci * HIN * HIN;
    float rin[2][10];                       // rows hi0, hi0-1; cols w0/2-1 .. w0/2+8
#pragma unroll
    for (int jy = 0; jy < 2; ++jy) {
      const int hh = hi0 - jy;
      const bool rok = (unsigned)hh < (unsigned)HIN;
      const float* rp = ip + hh * HIN;
      const int c0 = (w0 >> 1);
      if (rok) {
        rin[jy][0] = (c0 > 0) ? rp[c0 - 1] : 0.f;
        *(float4*)(&rin[jy][1]) = *(const float4*)(rp + c0);
        *(float4*)(&rin[jy][5]) = *(const float4*)(rp + c0 + 4);
        rin[jy][9] = (c0 + 8 < HIN) ? rp[c0 + 8] : 0.f;
      } else {
#pragma unroll
        for (int cc = 0; cc < 10; ++cc) rin[jy][cc] = 0.f;
      }
    }
    const float* wp = wl + ci * 16 * COCH;
#pragma unroll
    for (int jy = 0; jy < 2; ++jy) {
      const int ky = kyb + 2 * jy;          // uses row hi0-jy
#pragma unroll
      for (int kx = 0; kx < 4; ++kx) {
        const int p = (kx + 1) & 1;         // output col parity served by kx
        const int idx0 = ((p + 1 - kx) >> 1) + 1;
        float wv[COCH];
#pragma unroll
        for (int c = 0; c < COCH; c += 4)
          *(float4*)(wv + c) = *(const float4*)(wp + (ky * 4 + kx) * COCH + c);
#pragma unroll
        for (int m = 0; m < 8; ++m) {
          const float xv = rin[jy][idx0 + m];
#pragma unroll
          for (int c = 0; c < COCH; ++c)
            acc[2 * m + p][c] = fmaf(xv, wv[c], acc[2 * m + p][c]);
        }
      }
    }
  }
#pragma unroll
  for (int c = 0; c < COCH; ++c) {
    if (co0 + c < COUT) {
      float* op = out + (((size_t)img * COUT + co0 + c) * HOUT + r) * HOUT + w0;
#pragma unroll
      for (int m = 0; m < 16; ++m) {
        float v = acc[m][c];
        if (RELU_OUT) v = fmaxf(v, 0.f);
        op[m] = v;
      }
    }
  }
}

// ---------------- conv 1x1 + residual (in-place), 128->128, 32x32 ----------
// grid: (64 imgs, 8 co-chunks of 16), block 256; thread: 4 consecutive pos.
__global__ __launch_bounds__(256) void conv1x1res_k(
    const float* __restrict__ in, const float* __restrict__ w,
    const float* __restrict__ bias, float* __restrict__ io) {
  __shared__ float wl[128 * 16];  // [ci][co(16)]
  const int t = threadIdx.x;
  const int co0 = blockIdx.y * 16;
  for (int i = t; i < 2048; i += 256) {
    const int ci = i >> 4, co = i & 15;
    wl[i] = w[(co0 + co) * 128 + ci];
  }
  __syncthreads();
  const int img = blockIdx.x;
  float acc[4][16];
#pragma unroll
  for (int c = 0; c < 16; ++c) {
    const float b = bias[co0 + c];
#pragma unroll
    for (int p = 0; p < 4; ++p) acc[p][c] = b;
  }
  const float4* ip = (const float4*)(in + (size_t)img * 131072);
#pragma unroll 4
  for (int ci = 0; ci < 128; ++ci) {
    float xv[4];
    *(float4*)xv = ip[ci * 256 + t];
    float wv[16];
#pragma unroll
    for (int c = 0; c < 16; c += 4)
      *(float4*)(wv + c) = *(const float4*)(wl + ci * 16 + c);
#pragma unroll
    for (int p = 0; p < 4; ++p)
#pragma unroll
      for (int c = 0; c < 16; ++c) acc[p][c] = fmaf(xv[p], wv[c], acc[p][c]);
  }
  float4* iop = (float4*)(io + (size_t)img * 131072);
#pragma unroll
  for (int c = 0; c < 16; ++c) {
    float4 v = iop[(co0 + c) * 256 + t];
    v.x += acc[0][c]; v.y += acc[1][c]; v.z += acc[2][c]; v.w += acc[3][c];
    iop[(co0 + c) * 256 + t] = v;
  }
}

// ---------------- VQ -------------------------------------------------------
__global__ __launch_bounds__(256) void vq_prep_k(const float* __restrict__ emb,
    float* __restrict__ e2, float* __restrict__ lossAcc) {
  const int k = blockIdx.x * 256 + threadIdx.x;
  if (k < 512) {
    float s = 0.f;
#pragma unroll
    for (int d = 0; d < 32; ++d) { const float v = emb[k * 32 + d]; s = fmaf(v, v, s); }
    e2[k] = s;
  }
  if (k == 0) lossAcc[0] = 0.f;
}

// one spatial vector per thread; codebook via wave-uniform loads (L1 broadcast).
__global__ __launch_bounds__(256) void vq_k(
    const float* __restrict__ z, const float* __restrict__ emb,
    const float* __restrict__ e2, float* __restrict__ q,
    float* __restrict__ lossAcc) {
  const int n = blockIdx.x * 256 + threadIdx.x;
  const int img = n >> 10, pos = n & 1023;
  const float* zp = z + (size_t)img * 32768 + pos;
  float zv[32];
#pragma unroll
  for (int d = 0; d < 32; ++d) zv[d] = zp[d * 1024];
  float best = 3.4e38f;
  int bk = 0;
  const float4* ev = (const float4*)emb;
#pragma unroll 2
  for (int k = 0; k < 512; ++k) {
    float d0 = 0.f, d1 = 0.f, d2 = 0.f, d3 = 0.f;
#pragma unroll
    for (int j = 0; j < 8; ++j) {
      const float4 e = ev[k * 8 + j];
      d0 = fmaf(zv[4 * j + 0], e.x, d0);
      d1 = fmaf(zv[4 * j + 1], e.y, d1);
      d2 = fmaf(zv[4 * j + 2], e.z, d2);
      d3 = fmaf(zv[4 * j + 3], e.w, d3);
    }
    const float dist = fmaf(-2.f, (d0 + d1) + (d2 + d3), e2[k]);
    if (dist < best) { best = dist; bk = k; }   // strict <  => first argmin
  }
  float ls = 0.f;
  float* qp = q + (size_t)img * 32768 + pos;
#pragma unroll
  for (int d = 0; d < 32; ++d) {
    const float qd = emb[bk * 32 + d];
    qp[d * 1024] = qd;
    const float df = qd - zv[d];
    ls = fmaf(df, df, ls);
  }
#pragma unroll
  for (int off = 32; off > 0; off >>= 1) ls += __shfl_down(ls, off);
  __shared__ float wred[4];
  const int lane = threadIdx.x & 63, wid = threadIdx.x >> 6;
  if (lane == 0) wred[wid] = ls;
  __syncthreads();
  if (threadIdx.x == 0) atomicAdd(lossAcc, (wred[0] + wred[1]) + (wred[2] + wred[3]));
}

__global__ void loss_fin_k(const float* __restrict__ lossAcc, float* __restrict__ o) {
  o[0] = 1.25f * lossAcc[0] * (1.0f / 2097152.0f);
}

// ---------------------------------------------------------------------------
extern "C" void kernel_launch(void* const* d_in, const int* in_sizes, int n_in,
                              void* d_out, int out_size, void* d_ws, size_t ws_size,
                              hipStream_t stream) {
  (void)in_sizes; (void)n_in; (void)out_size; (void)ws_size;
  const float* x      = (const float*)d_in[0];
  const float* ec0_w  = (const float*)d_in[1];  const float* ec0_b = (const float*)d_in[2];
  const float* ec1_w  = (const float*)d_in[3];  const float* ec1_b = (const float*)d_in[4];
  const float* er1a_w = (const float*)d_in[5];  const float* er1a_b = (const float*)d_in[6];
  const float* er1b_w = (const float*)d_in[7];  const float* er1b_b = (const float*)d_in[8];
  const float* er2a_w = (const float*)d_in[9];  const float* er2a_b = (const float*)d_in[10];
  const float* er2b_w = (const float*)d_in[11]; const float* er2b_b = (const float*)d_in[12];
  const float* ec2_w  = (const float*)d_in[13]; const float* ec2_b = (const float*)d_in[14];
  const float* emb    = (const float*)d_in[15];
  const float* dc0_w  = (const float*)d_in[16]; const float* dc0_b = (const float*)d_in[17];
  const float* dr1a_w = (const float*)d_in[18]; const float* dr1a_b = (const float*)d_in[19];
  const float* dr1b_w = (const float*)d_in[20]; const float* dr1b_b = (const float*)d_in[21];
  const float* dr2a_w = (const float*)d_in[22]; const float* dr2a_b = (const float*)d_in[23];
  const float* dr2b_w = (const float*)d_in[24]; const float* dr2b_b = (const float*)d_in[25];
  const float* dt1_w  = (const float*)d_in[26]; const float* dt1_b = (const float*)d_in[27];
  const float* dt2_w  = (const float*)d_in[28]; const float* dt2_b = (const float*)d_in[29];
  float* out = (float*)d_out;
  float* ws  = (float*)d_ws;

  // workspace layout (floats); C/Z/Q overlap the dead ec0 buffer A.
  float* A    = ws;                    // 16777216 (ec0 out; later dt1 out)
  float* B    = ws + 16777216;         //  8388608 (main 128ch stream)
  float* C    = A;                     //  8388608 (res 3x3 tmp)
  float* Z    = A + 8388608;           //  2097152 (encoder z)
  float* Q    = A + 10485760;          //  2097152 (quantized)
  float* E2   = ws + 25165824;         //      512
  float* LACC = ws + 25166336;         //        1

  // encoder
  conv4x4s2_k<3, 64, 64, true><<<dim3(128, 8), 256, 0, stream>>>(x, ec0_w, ec0_b, A);
  conv4x4s2_k<64, 128, 32, true><<<dim3(32, 16), 256, 0, stream>>>(A, ec1_w, ec1_b, B);
  conv3x3_k<128, 128, true, true><<<dim3(64, 16), 256, 0, stream>>>(B, er1a_w, er1a_b, C);
  conv1x1res_k<<<dim3(64, 8), 256, 0, stream>>>(C, er1b_w, er1b_b, B);
  conv3x3_k<128, 128, true, true><<<dim3(64, 16), 256, 0, stream>>>(B, er2a_w, er2a_b, C);
  conv1x1res_k<<<dim3(64, 8), 256, 0, stream>>>(C, er2b_w, er2b_b, B);
  conv3x3_k<128, 32, false, false><<<dim3(64, 4), 256, 0, stream>>>(B, ec2_w, ec2_b, Z);
  // vector quantizer
  vq_prep_k<<<2, 256, 0, stream>>>(emb, E2, LACC);
  vq_k<<<256, 256, 0, stream>>>(Z, emb, E2, Q, LACC);
  // decoder
  conv3x3_k<32, 128, false, false><<<dim3(64, 16), 256, 0, stream>>>(Q, dc0_w, dc0_b, B);
  conv3x3_k<128, 128, true, true><<<dim3(64, 16), 256, 0, stream>>>(B, dr1a_w, dr1a_b, C);
  conv1x1res_k<<<dim3(64, 8), 256, 0, stream>>>(C, dr1b_w, dr1b_b, B);
  conv3x3_k<128, 128, true, true><<<dim3(64, 16), 256, 0, stream>>>(B, dr2a_w, dr2a_b, C);
  conv1x1res_k<<<dim3(64, 8), 256, 0, stream>>>(C, dr2b_w, dr2b_b, B);
  convT4x4s2_k<128, 64, 8, 64, true><<<dim3(64, 8), 256, 0, stream>>>(B, dt1_w, dt1_b, A);
  convT4x4s2_k<64, 3, 4, 128, false><<<dim3(256, 1), 256, 0, stream>>>(A, dt2_w, dt2_b, out);
  // loss
  loss_fin_k<<<1, 1, 0, stream>>>(LACC, out + 3145728);
}